// Round 12
// baseline (611.470 us; speedup 1.0000x reference)
//
#include <hip/hip_runtime.h>
#include <hip/hip_bf16.h>
#include <hip/hip_cooperative_groups.h>

namespace cg = cooperative_groups;

// ---- problem constants ----
#define S_    4096
#define D_    1024
#define H_    8
#define DH_   64
#define ETA_  4
#define R_    8
#define E_    256
#define NC_   256          // scan chunks
#define LC_   (S_/NC_)     // 16 steps per chunk
#define N1_   2688         // padded N for GEMM1 (21*128)
#define NKQV_ 2560
#define NP_   96
#define PIF   3.14159265358979323846

// prep_all block-range boundaries
#define PB_CVT    2048                 // inputs fp32->fp16 hi/lo split (row-major)
#define PB_TRWK   (PB_CVT + 640)       // W_kqv transpose -> frag-linear (16 k-tiles x 40 n-tiles)
#define PB_TRWP   (PB_TRWK + 32)       // W_p transpose (16 x 2)
#define PB_TRWPJ  (PB_TRWP + 128)      // W_proj transpose (8 x 16)
#define PB_OC     (PB_TRWPJ + 128)     // oscillator table
#define PB_BIAS   (PB_OC + 11)         // bias1
#define PB_TOTAL  PB_BIAS

typedef unsigned short u16;
typedef unsigned int   u32;
typedef _Float16 v8h __attribute__((ext_vector_type(8)));
typedef float v4f __attribute__((ext_vector_type(4)));

__device__ __forceinline__ u16 f2h(float f) {
    _Float16 h = (_Float16)f;                 // RTN
    return __builtin_bit_cast(unsigned short, h);
}
__device__ __forceinline__ float h2f(u16 u) {
    return (float)__builtin_bit_cast(_Float16, u);
}
__device__ __forceinline__ float sigm(float x) { return 1.f / (1.f + expf(-x)); }

// async global->LDS, 16 B per lane; LDS dest = wave-uniform base + lane*16
#define GLD16(gp, lp) __builtin_amdgcn_global_load_lds( \
    (const __attribute__((address_space(1))) u32*)(const void*)(gp), \
    (__attribute__((address_space(3))) u32*)(void*)(lp), 16, 0, 0)

// Fragment-linear layout (B operands): tile (nt = nrow/16, kt = k/32) of 512 fp16 = 1 KB at
// ((nt*nkt + kt) << 9); element at lane*8 + j, lane=(nrow&15)+((k&31)>>3)*16, j=k&7.

// ---- transpose 64x64 tile -> fp16 frag-linear ----
__device__ __forceinline__ void tr64h(float (*tile)[65], const float* __restrict__ src, int K, int Nsrc,
                                      u16* __restrict__ dH, int rowOff, int k0, int n0, int t) {
    const int cc = t & 63, rr = t >> 6;
    const int nkt = K >> 5;
    #pragma unroll
    for (int i = 0; i < 16; ++i) {
        int kk = rr * 16 + i;
        tile[kk][cc] = (n0 + cc < Nsrc) ? src[(size_t)(k0 + kk) * Nsrc + n0 + cc] : 0.f;
    }
    __syncthreads();
    #pragma unroll
    for (int i = 0; i < 16; ++i) {
        int nn = rr * 16 + i;
        int nrow = rowOff + n0 + nn, k = k0 + cc;
        int nt = nrow >> 4, kt = k >> 5;
        int ln = (nrow & 15) + (((k & 31) >> 3) << 4), j = k & 7;
        dH[((size_t)(nt * nkt + kt) << 9) + ln * 8 + j] = f2h(tile[cc][nn]);
    }
}

// ---- fused prep: cvt inputs (hi/lo row-major), 3 transposes (frag), oscillator, bias ----
__global__ __launch_bounds__(256) void prep_all(const float* __restrict__ inputs,
                                                const float* __restrict__ Wk, const float* __restrict__ Wp,
                                                const float* __restrict__ Wproj,
                                                const float* __restrict__ bk, const float* __restrict__ bp,
                                                const float* __restrict__ tick,
                                                u16* __restrict__ AbfH, u16* __restrict__ AbfL,
                                                u16* __restrict__ BTh, u16* __restrict__ WpTh,
                                                float* __restrict__ biasb, float* __restrict__ OC) {
    __shared__ float tile[64][65];
    const int b = blockIdx.x, t = threadIdx.x;
    if (b < PB_CVT) {
        int i = b * 256 + t;                       // 8 elems per thread, row-major
        const float4* xp = (const float4*)inputs;
        float4 a = xp[2 * i], bb = xp[2 * i + 1];
        float v[8] = {a.x, a.y, a.z, a.w, bb.x, bb.y, bb.z, bb.w};
        unsigned hh[8], ll[8];
        #pragma unroll
        for (int j = 0; j < 8; ++j) {
            u16 h = f2h(v[j]);
            hh[j] = h;
            ll[j] = f2h(v[j] - h2f(h));
        }
        uint4 rh, rl;
        rh.x = hh[0] | (hh[1] << 16); rh.y = hh[2] | (hh[3] << 16);
        rh.z = hh[4] | (hh[5] << 16); rh.w = hh[6] | (hh[7] << 16);
        rl.x = ll[0] | (ll[1] << 16); rl.y = ll[2] | (ll[3] << 16);
        rl.z = ll[4] | (ll[5] << 16); rl.w = ll[6] | (ll[7] << 16);
        ((uint4*)AbfH)[i] = rh;
        ((uint4*)AbfL)[i] = rl;
    } else if (b < PB_TRWK) {
        int i = b - PB_CVT;
        tr64h(tile, Wk, D_, NKQV_, BTh, 0, (i % 16) * 64, (i / 16) * 64, t);
    } else if (b < PB_TRWP) {
        int i = b - PB_TRWK;
        tr64h(tile, Wp, D_, NP_, BTh, NKQV_, (i % 16) * 64, (i / 16) * 64, t);
    } else if (b < PB_TRWPJ) {
        int i = b - PB_TRWP;
        tr64h(tile, Wproj, 512, D_, WpTh, 0, (i % 8) * 64, (i / 8) * 64, t);
    } else if (b < PB_OC) {
        int idx = (b - PB_TRWPJ) * 256 + t;
        int tt = idx / R_, r = idx % R_;
        float start = (float)(-PIF), stop = (float)PIF;
        float step = __fdiv_rn(__fsub_rn(stop, start), 7.0f);
        float om = __fadd_rn(start, __fmul_rn((float)r, step));
        float tk = __fadd_rn(tick[0], (float)(tt + 1));
        OC[idx] = cosf(__fmul_rn(tk, om));
    } else {
        int n = (b - PB_OC) * 256 + t;
        if (n < N1_)
            biasb[n] = n < NKQV_ ? bk[n] : (n < NKQV_ + NP_ ? bp[n - NKQV_] : 0.f);
    }
}

// ---- hybrid split-fp16 x2 GEMM (R9-proven, 60.8 us): A (hi/lo) via LDS double-buffered
// global_load_lds, B (hi) direct from global frag-linear, register-double-buffered.
// Y = (Ah+Al)*Bh + bias. 128x128 tile, 4 waves, BK=32. actMode=1: fused activations.
__global__ __launch_bounds__(256, 3) void gemm_x2_hyb(const u16* __restrict__ Ah, const u16* __restrict__ Al,
                                                      const u16* __restrict__ BTf,
                                                      const float* __restrict__ bias,
                                                      float* __restrict__ Yo, int ldy, int Kdim, int actMode) {
    __shared__ __align__(16) u16 lds[2][2][4096];   // 2 buf x {AH,AL} x [128 rows][32 k] = 32 KB
    const int tid = threadIdx.x, lane = tid & 63, w = tid >> 6;
    const int mw = (w >> 1) * 64, nw = (w & 1) * 64;
    const int l15 = lane & 15, lk8 = lane >> 4;
    const int lke = (lk8 ^ (l15 & 3) ^ ((l15 >> 2) & 3)) * 8;   // swizzled k-slot for A frag reads
    // XCD-aware block swizzle (total blocks % 8 == 0)
    const int gx = gridDim.x;
    const int nb = gx * gridDim.y;
    const int orig = blockIdx.y * gx + blockIdx.x;
    const int per = nb >> 3;
    const int swz = (orig & 7) * per + (orig >> 3);
    const int m0 = (swz / gx) * 128, n0 = (swz % gx) * 128;
    const int nkt = Kdim >> 5;

    auto stageA = [&](int buf, int k0) {
        #pragma unroll
        for (int c = 0; c < 2; ++c) {
            int u = tid + (c << 8);                               // 0..511 chunk index
            int row = u >> 2, s = u & 3;
            int kc = ((s ^ (row & 3) ^ ((row >> 2) & 3)) << 3);   // pre-swizzled global chunk
            int wub = ((u & ~63) << 3);                           // wave-uniform LDS elem offset
            size_t offA = (size_t)(m0 + row) * Kdim + k0 + kc;
            GLD16(Ah + offA, &lds[buf][0][wub]);
            GLD16(Al + offA, &lds[buf][1][wub]);
        }
    };

    // B frag-linear bases (per-wave column block nw)
    size_t bBase[4];
    #pragma unroll
    for (int f = 0; f < 4; ++f)
        bBase[f] = ((size_t)(((n0 + nw) >> 4) + f) * nkt << 9) + lane * 8;

    v4f acc[4][4] = {};
    stageA(0, 0);
    v8h bcur[4];
    #pragma unroll
    for (int f = 0; f < 4; ++f) bcur[f] = *(const v8h*)(BTf + bBase[f]);
    int cur = 0;
    for (int kt = 0; kt < nkt; ++kt) {
        __syncthreads();                      // buf[cur] A staged; prev frag reads done
        if (kt + 1 < nkt) stageA(cur ^ 1, (kt + 1) << 5);
        v8h bnxt[4];
        if (kt + 1 < nkt) {
            const size_t ko = (size_t)(kt + 1) << 9;
            #pragma unroll
            for (int f = 0; f < 4; ++f) bnxt[f] = *(const v8h*)(BTf + bBase[f] + ko);
        }
        v8h afh[4], afl[4];
        #pragma unroll
        for (int f = 0; f < 4; ++f) {
            int ra = (mw + f * 16 + l15) * 32 + lke;
            afh[f] = *(const v8h*)&lds[cur][0][ra];
            afl[f] = *(const v8h*)&lds[cur][1][ra];
        }
        #pragma unroll
        for (int i = 0; i < 4; ++i)
            #pragma unroll
            for (int j = 0; j < 4; ++j)
                acc[i][j] = __builtin_amdgcn_mfma_f32_16x16x32_f16(afh[i], bcur[j], acc[i][j], 0, 0, 0);
        #pragma unroll
        for (int i = 0; i < 4; ++i)
            #pragma unroll
            for (int j = 0; j < 4; ++j)
                acc[i][j] = __builtin_amdgcn_mfma_f32_16x16x32_f16(afl[i], bcur[j], acc[i][j], 0, 0, 0);
        if (kt + 1 < nkt) {
            #pragma unroll
            for (int f = 0; f < 4; ++f) bcur[f] = bnxt[f];
        }
        cur ^= 1;
    }
    #pragma unroll
    for (int i = 0; i < 4; ++i) {
        int row0 = m0 + mw + i * 16 + lk8 * 4;   // C/D: col=lane&15, row=(lane>>4)*4+reg (m89)
        #pragma unroll
        for (int j = 0; j < 4; ++j) {
            int col = n0 + nw + j * 16 + l15;
            float bv = bias[col];
            int ct = 2;                            // 2 = identity
            if (actMode) {
                if (col < NKQV_) ct = (col % 320) >> 6;            // 0 k,1 q,2 v,3 b,4 g
                else { int m12 = (col - NKQV_) % 12; ct = (m12 < 8) ? 0 : 3; }  // p1/p2 relu, p3 sigm
            }
            #pragma unroll
            for (int rg = 0; rg < 4; ++rg) {
                float y = acc[i][j][rg] + bv;
                if (ct == 0 || ct == 1) y = fmaxf(y, 0.f);
                else if (ct >= 3) y = sigm(y);
                Yo[(size_t)(row0 + rg) * ldy + col] = y;
            }
        }
    }
}

// ---- fused 3-phase scan, ONE cooperative kernel (2048 one-wave blocks, co-resident) ----
// phase1: per (chunk,head) local scan -> CL;  grid.sync
// phase2: blocks 0..351 element-parallel combine -> CI (CL/CI are per-XCD L2-resident);  grid.sync
// phase3: re-scan with carry-in -> attn (fp16 hi/lo)
__global__ __launch_bounds__(64, 2) void scan_fused(const float* __restrict__ Y1, const float* __restrict__ OC,
                                                    const int* __restrict__ term,
                                                    const float* __restrict__ TK, const float* __restrict__ TV,
                                                    const float* __restrict__ SP,
                                                    float* __restrict__ CL, float* __restrict__ CI,
                                                    u16* __restrict__ attnH, u16* __restrict__ attnL) {
    cg::grid_group grid = cg::this_grid();
    const int b = blockIdx.x, c = b / H_, h = b % H_, lane = threadIdx.x;

    // ======== phase 1: local scan from zero + decay products ========
    {
        float kc[R_][ETA_] = {}, vc[R_] = {}, sc[ETA_] = {};
        float Pg[ETA_] = {1.f, 1.f, 1.f, 1.f}, Pb = 1.f;
        for (int t = c * LC_; t < c * LC_ + LC_; ++t) {
            const float* row = Y1 + (size_t)t * N1_;
            const float* bh = row + h * 320;
            float rk = bh[lane], vv = bh[128 + lane], sb = bh[192 + lane], sg = bh[256 + lane];
            const float* pp = row + NKQV_ + h * 12;
            float nt = 1.f - (float)term[t];
            float vals = vv * sb, dbv = (1.f - sb) * nt;
            float occ[R_];
            #pragma unroll
            for (int r = 0; r < R_; ++r) occ[r] = OC[t * R_ + r];
            #pragma unroll
            for (int e = 0; e < ETA_; ++e) {
                float gam = sg * pp[8 + e];
                float kg = rk * pp[e] * gam;
                float dgv = (1.f - gam) * nt;
                sc[e] = dgv * sc[e] + kg;
                Pg[e] *= dgv;
                #pragma unroll
                for (int r = 0; r < R_; ++r) kc[r][e] = dgv * kc[r][e] + kg * occ[r];
            }
            Pb *= dbv;
            #pragma unroll
            for (int r = 0; r < R_; ++r) vc[r] = dbv * vc[r] + vals * occ[r];
        }
        float* out = CL + (size_t)b * 49 * 64;
        #pragma unroll
        for (int r = 0; r < R_; ++r)
            #pragma unroll
            for (int e = 0; e < ETA_; ++e) out[(r * 4 + e) * 64 + lane] = kc[r][e];
        #pragma unroll
        for (int r = 0; r < R_; ++r) out[(32 + r) * 64 + lane] = vc[r];
        #pragma unroll
        for (int e = 0; e < ETA_; ++e) out[(40 + e) * 64 + lane] = sc[e];
        #pragma unroll
        for (int e = 0; e < ETA_; ++e) out[(44 + e) * 64 + lane] = Pg[e];
        out[48 * 64 + lane] = Pb;
    }
    grid.sync();

    // ======== phase 2: sequential chunk-combine, blocks 0..351 ========
    if (b < (H_ * 44 * 64) / 64) {
        const int gid = b * 64 + lane;
        const int hv = gid >> 6;
        const int hh = hv / 44;
        const int v = hv % 44;
        float x;
        int dvec;
        if (v < 32) {
            int r = v >> 2, e = v & 3;
            x = TK[((size_t)r * H_ + hh) * E_ + (gid & 63) * 4 + e];
            dvec = 44 + e;
        } else if (v < 40) {
            int r = v - 32;
            x = TV[((size_t)r * H_ + hh) * DH_ + (gid & 63)];
            dvec = 48;
        } else {
            int e = v - 40;
            x = SP[(size_t)hh * E_ + (gid & 63) * 4 + e];
            dvec = 44 + e;
        }
        const float* clb = CL + (size_t)hh * 49 * 64 + (size_t)v * 64 + (gid & 63);
        const float* dcb = CL + (size_t)hh * 49 * 64 + (size_t)dvec * 64 + (gid & 63);
        float* cib = CI + (size_t)hh * 44 * 64 + (size_t)v * 64 + (gid & 63);
        const size_t sCL = (size_t)H_ * 49 * 64;
        const size_t sCI = (size_t)H_ * 44 * 64;
        #pragma unroll 8
        for (int cc = 0; cc < NC_; ++cc) {
            cib[(size_t)cc * sCI] = x;
            float cl = clb[(size_t)cc * sCL];
            float d  = dcb[(size_t)cc * sCL];
            x = fmaf(d, x, cl);
        }
    }
    grid.sync();

    // ======== phase 3: re-scan with carry-in, emit attn ========
    {
        float kc[R_][ETA_], vc[R_], sc[ETA_];
        const float* ci = CI + (size_t)b * 44 * 64;
        #pragma unroll
        for (int r = 0; r < R_; ++r)
            #pragma unroll
            for (int e = 0; e < ETA_; ++e) kc[r][e] = ci[(r * 4 + e) * 64 + lane];
        #pragma unroll
        for (int r = 0; r < R_; ++r) vc[r] = ci[(32 + r) * 64 + lane];
        #pragma unroll
        for (int e = 0; e < ETA_; ++e) sc[e] = ci[(40 + e) * 64 + lane];
        for (int t = c * LC_; t < c * LC_ + LC_; ++t) {
            const float* row = Y1 + (size_t)t * N1_;
            const float* bh = row + h * 320;
            float rk = bh[lane], rq = bh[64 + lane], vv = bh[128 + lane], sb = bh[192 + lane], sg = bh[256 + lane];
            const float* pp = row + NKQV_ + h * 12;
            float nt = 1.f - (float)term[t];
            float vals = vv * sb, dbv = (1.f - sb) * nt;
            float occ[R_];
            #pragma unroll
            for (int r = 0; r < R_; ++r) occ[r] = OC[t * R_ + r];
            float qe[ETA_];
            #pragma unroll
            for (int e = 0; e < ETA_; ++e) {
                float gam = sg * pp[8 + e];
                float kg = rk * pp[e] * gam;
                float dgv = (1.f - gam) * nt;
                qe[e] = rq * pp[4 + e];
                sc[e] = dgv * sc[e] + kg;
                #pragma unroll
                for (int r = 0; r < R_; ++r) kc[r][e] = dgv * kc[r][e] + kg * occ[r];
            }
            #pragma unroll
            for (int r = 0; r < R_; ++r) vc[r] = dbv * vc[r] + vals * occ[r];
            float kdq[R_], nrm = 0.f;
            #pragma unroll
            for (int r = 0; r < R_; ++r) {
                float s = 0.f;
                #pragma unroll
                for (int e = 0; e < ETA_; ++e) s += kc[r][e] * qe[e];
                kdq[r] = s;
            }
            #pragma unroll
            for (int e = 0; e < ETA_; ++e) nrm += sc[e] * qe[e];
            #pragma unroll
            for (int m = 1; m < 64; m <<= 1) {
                #pragma unroll
                for (int r = 0; r < R_; ++r) kdq[r] += __shfl_xor(kdq[r], m);
                nrm += __shfl_xor(nrm, m);
            }
            float kv = 0.f;
            #pragma unroll
            for (int r = 0; r < R_; ++r) kv += vc[r] * kdq[r];
            float at = kv / (2.f * R_ * nrm + 1e-5f);
            size_t oi = (size_t)t * (H_ * DH_) + h * DH_ + lane;
            u16 hi = f2h(at);
            attnH[oi] = hi;
            attnL[oi] = f2h(at - h2f(hi));
        }
    }
}

extern "C" void kernel_launch(void* const* d_in, const int* in_sizes, int n_in,
                              void* d_out, int out_size, void* d_ws, size_t ws_size,
                              hipStream_t stream) {
    const float* inputs = (const float*)d_in[0];
    const int*   term   = (const int*)d_in[1];
    const float* Wk     = (const float*)d_in[2];
    const float* bk     = (const float*)d_in[3];
    const float* Wp     = (const float*)d_in[4];
    const float* bp     = (const float*)d_in[5];
    const float* Wproj  = (const float*)d_in[6];
    const float* bproj  = (const float*)d_in[7];
    const float* TK     = (const float*)d_in[8];
    const float* TV     = (const float*)d_in[9];
    const float* SP     = (const float*)d_in[10];
    const float* tick   = (const float*)d_in[11];
    float* out = (float*)d_out;

    char* w = (char*)d_ws;
    u16* AbfH   = (u16*)w;  w += (size_t)S_ * D_ * 2;          // 8 MB  (row-major)
    u16* AbfL   = (u16*)w;  w += (size_t)S_ * D_ * 2;          // 8 MB
    u16* BTh    = (u16*)w;  w += (size_t)N1_ * D_ * 2;         // 5.5 MB (frag-linear)
    u16* WpTh   = (u16*)w;  w += (size_t)D_ * 512 * 2;         // 1 MB   (frag-linear)
    u16* attnH  = (u16*)w;  w += (size_t)S_ * 512 * 2;         // 4 MB   (row-major)
    u16* attnL  = (u16*)w;  w += (size_t)S_ * 512 * 2;         // 4 MB
    float* biasb = (float*)w; w += (size_t)N1_ * 4;
    float* Y1   = (float*)w; w += (size_t)S_ * N1_ * 4;        // 44 MB
    float* OC   = (float*)w; w += (size_t)S_ * R_ * 4;
    float* CL   = (float*)w; w += (size_t)NC_ * H_ * 49 * 64 * 4;  // 25.7 MB
    float* CI   = (float*)w; w += (size_t)NC_ * H_ * 44 * 64 * 4;  // 23.1 MB

    prep_all<<<PB_TOTAL, 256, 0, stream>>>(inputs, Wk, Wp, Wproj, bk, bp, tick,
                                           AbfH, AbfL, BTh, WpTh, biasb, OC);
    gemm_x2_hyb<<<dim3(N1_ / 128, S_ / 128), 256, 0, stream>>>(AbfH, AbfL, BTh, biasb, Y1, N1_, D_, 1);
    {
        void* args[] = {(void*)&Y1, (void*)&OC, (void*)&term, (void*)&TK, (void*)&TV, (void*)&SP,
                        (void*)&CL, (void*)&CI, (void*)&attnH, (void*)&attnL};
        hipLaunchCooperativeKernel((void*)scan_fused, dim3(NC_ * H_), dim3(64), args, 0, stream);
    }
    gemm_x2_hyb<<<dim3(1024 / 128, S_ / 128), 256, 0, stream>>>(attnH, attnL, WpTh, bproj, out, D_, 512, 0);
}

// Round 13
// 156.361 us; speedup vs baseline: 3.9106x; 3.9106x over previous
//
#include <hip/hip_runtime.h>
#include <hip/hip_bf16.h>

// ---- problem constants ----
#define S_    4096
#define D_    1024
#define H_    8
#define DH_   64
#define ETA_  4
#define R_    8
#define E_    256
#define NC_   256          // scan chunks
#define LC_   (S_/NC_)     // 16 steps per chunk
#define N1_   2688         // padded N for GEMM1 (21*128)
#define NKQV_ 2560
#define NP_   96
#define PIF   3.14159265358979323846

// prep_all block-range boundaries
#define PB_CVT    2048                 // inputs fp32->fp16 hi/lo split (row-major)
#define PB_TRWK   (PB_CVT + 640)       // W_kqv transpose -> frag-linear (16 k-tiles x 40 n-tiles)
#define PB_TRWP   (PB_TRWK + 32)       // W_p transpose (16 x 2)
#define PB_TRWPJ  (PB_TRWP + 128)      // W_proj transpose (8 x 16)
#define PB_OC     (PB_TRWPJ + 128)     // oscillator table
#define PB_BIAS   (PB_OC + 11)         // bias1
#define PB_TOTAL  PB_BIAS

typedef unsigned short u16;
typedef unsigned int   u32;
typedef _Float16 v8h __attribute__((ext_vector_type(8)));
typedef float v4f __attribute__((ext_vector_type(4)));

__device__ __forceinline__ u16 f2h(float f) {
    _Float16 h = (_Float16)f;                 // RTN
    return __builtin_bit_cast(unsigned short, h);
}
__device__ __forceinline__ float h2f(u16 u) {
    return (float)__builtin_bit_cast(_Float16, u);
}
__device__ __forceinline__ float sigm(float x) { return 1.f / (1.f + expf(-x)); }

// async global->LDS, 16 B per lane; LDS dest = wave-uniform base + lane*16
#define GLD16(gp, lp) __builtin_amdgcn_global_load_lds( \
    (const __attribute__((address_space(1))) u32*)(const void*)(gp), \
    (__attribute__((address_space(3))) u32*)(void*)(lp), 16, 0, 0)

// Fragment-linear layout (B operands): tile (nt = nrow/16, kt = k/32) of 512 fp16 = 1 KB at
// ((nt*nkt + kt) << 9); element at lane*8 + j, lane=(nrow&15)+((k&31)>>3)*16, j=k&7.

// ---- transpose 64x64 tile -> fp16 frag-linear ----
__device__ __forceinline__ void tr64h(float (*tile)[65], const float* __restrict__ src, int K, int Nsrc,
                                      u16* __restrict__ dH, int rowOff, int k0, int n0, int t) {
    const int cc = t & 63, rr = t >> 6;
    const int nkt = K >> 5;
    #pragma unroll
    for (int i = 0; i < 16; ++i) {
        int kk = rr * 16 + i;
        tile[kk][cc] = (n0 + cc < Nsrc) ? src[(size_t)(k0 + kk) * Nsrc + n0 + cc] : 0.f;
    }
    __syncthreads();
    #pragma unroll
    for (int i = 0; i < 16; ++i) {
        int nn = rr * 16 + i;
        int nrow = rowOff + n0 + nn, k = k0 + cc;
        int nt = nrow >> 4, kt = k >> 5;
        int ln = (nrow & 15) + (((k & 31) >> 3) << 4), j = k & 7;
        dH[((size_t)(nt * nkt + kt) << 9) + ln * 8 + j] = f2h(tile[cc][nn]);
    }
}

// ---- fused prep: cvt inputs (hi/lo row-major), 3 transposes (frag), oscillator, bias ----
__global__ __launch_bounds__(256) void prep_all(const float* __restrict__ inputs,
                                                const float* __restrict__ Wk, const float* __restrict__ Wp,
                                                const float* __restrict__ Wproj,
                                                const float* __restrict__ bk, const float* __restrict__ bp,
                                                const float* __restrict__ tick,
                                                u16* __restrict__ AbfH, u16* __restrict__ AbfL,
                                                u16* __restrict__ BTh, u16* __restrict__ WpTh,
                                                float* __restrict__ biasb, float* __restrict__ OC) {
    __shared__ float tile[64][65];
    const int b = blockIdx.x, t = threadIdx.x;
    if (b < PB_CVT) {
        int i = b * 256 + t;                       // 8 elems per thread, row-major
        const float4* xp = (const float4*)inputs;
        float4 a = xp[2 * i], bb = xp[2 * i + 1];
        float v[8] = {a.x, a.y, a.z, a.w, bb.x, bb.y, bb.z, bb.w};
        unsigned hh[8], ll[8];
        #pragma unroll
        for (int j = 0; j < 8; ++j) {
            u16 h = f2h(v[j]);
            hh[j] = h;
            ll[j] = f2h(v[j] - h2f(h));
        }
        uint4 rh, rl;
        rh.x = hh[0] | (hh[1] << 16); rh.y = hh[2] | (hh[3] << 16);
        rh.z = hh[4] | (hh[5] << 16); rh.w = hh[6] | (hh[7] << 16);
        rl.x = ll[0] | (ll[1] << 16); rl.y = ll[2] | (ll[3] << 16);
        rl.z = ll[4] | (ll[5] << 16); rl.w = ll[6] | (ll[7] << 16);
        ((uint4*)AbfH)[i] = rh;
        ((uint4*)AbfL)[i] = rl;
    } else if (b < PB_TRWK) {
        int i = b - PB_CVT;
        tr64h(tile, Wk, D_, NKQV_, BTh, 0, (i % 16) * 64, (i / 16) * 64, t);
    } else if (b < PB_TRWP) {
        int i = b - PB_TRWK;
        tr64h(tile, Wp, D_, NP_, BTh, NKQV_, (i % 16) * 64, (i / 16) * 64, t);
    } else if (b < PB_TRWPJ) {
        int i = b - PB_TRWP;
        tr64h(tile, Wproj, 512, D_, WpTh, 0, (i % 8) * 64, (i / 8) * 64, t);
    } else if (b < PB_OC) {
        int idx = (b - PB_TRWPJ) * 256 + t;
        int tt = idx / R_, r = idx % R_;
        float start = (float)(-PIF), stop = (float)PIF;
        float step = __fdiv_rn(__fsub_rn(stop, start), 7.0f);
        float om = __fadd_rn(start, __fmul_rn((float)r, step));
        float tk = __fadd_rn(tick[0], (float)(tt + 1));
        OC[idx] = cosf(__fmul_rn(tk, om));
    } else {
        int n = (b - PB_OC) * 256 + t;
        if (n < N1_)
            biasb[n] = n < NKQV_ ? bk[n] : (n < NKQV_ + NP_ ? bp[n - NKQV_] : 0.f);
    }
}

// ---- hybrid split-fp16 x2 GEMM (R9-proven, 60.8 us): A (hi/lo) via LDS double-buffered
// global_load_lds, B (hi) direct from global frag-linear, register-double-buffered.
// Y = (Ah+Al)*Bh + bias. 128x128 tile, 4 waves, BK=32. actMode=1: fused activations.
__global__ __launch_bounds__(256, 3) void gemm_x2_hyb(const u16* __restrict__ Ah, const u16* __restrict__ Al,
                                                      const u16* __restrict__ BTf,
                                                      const float* __restrict__ bias,
                                                      float* __restrict__ Yo, int ldy, int Kdim, int actMode) {
    __shared__ __align__(16) u16 lds[2][2][4096];   // 2 buf x {AH,AL} x [128 rows][32 k] = 32 KB
    const int tid = threadIdx.x, lane = tid & 63, w = tid >> 6;
    const int mw = (w >> 1) * 64, nw = (w & 1) * 64;
    const int l15 = lane & 15, lk8 = lane >> 4;
    const int lke = (lk8 ^ (l15 & 3) ^ ((l15 >> 2) & 3)) * 8;   // swizzled k-slot for A frag reads
    // XCD-aware block swizzle (total blocks % 8 == 0)
    const int gx = gridDim.x;
    const int nb = gx * gridDim.y;
    const int orig = blockIdx.y * gx + blockIdx.x;
    const int per = nb >> 3;
    const int swz = (orig & 7) * per + (orig >> 3);
    const int m0 = (swz / gx) * 128, n0 = (swz % gx) * 128;
    const int nkt = Kdim >> 5;

    auto stageA = [&](int buf, int k0) {
        #pragma unroll
        for (int c = 0; c < 2; ++c) {
            int u = tid + (c << 8);                               // 0..511 chunk index
            int row = u >> 2, s = u & 3;
            int kc = ((s ^ (row & 3) ^ ((row >> 2) & 3)) << 3);   // pre-swizzled global chunk
            int wub = ((u & ~63) << 3);                           // wave-uniform LDS elem offset
            size_t offA = (size_t)(m0 + row) * Kdim + k0 + kc;
            GLD16(Ah + offA, &lds[buf][0][wub]);
            GLD16(Al + offA, &lds[buf][1][wub]);
        }
    };

    // B frag-linear bases (per-wave column block nw)
    size_t bBase[4];
    #pragma unroll
    for (int f = 0; f < 4; ++f)
        bBase[f] = ((size_t)(((n0 + nw) >> 4) + f) * nkt << 9) + lane * 8;

    v4f acc[4][4] = {};
    stageA(0, 0);
    v8h bcur[4];
    #pragma unroll
    for (int f = 0; f < 4; ++f) bcur[f] = *(const v8h*)(BTf + bBase[f]);
    int cur = 0;
    for (int kt = 0; kt < nkt; ++kt) {
        __syncthreads();                      // buf[cur] A staged; prev frag reads done
        if (kt + 1 < nkt) stageA(cur ^ 1, (kt + 1) << 5);
        v8h bnxt[4];
        if (kt + 1 < nkt) {
            const size_t ko = (size_t)(kt + 1) << 9;
            #pragma unroll
            for (int f = 0; f < 4; ++f) bnxt[f] = *(const v8h*)(BTf + bBase[f] + ko);
        }
        v8h afh[4], afl[4];
        #pragma unroll
        for (int f = 0; f < 4; ++f) {
            int ra = (mw + f * 16 + l15) * 32 + lke;
            afh[f] = *(const v8h*)&lds[cur][0][ra];
            afl[f] = *(const v8h*)&lds[cur][1][ra];
        }
        #pragma unroll
        for (int i = 0; i < 4; ++i)
            #pragma unroll
            for (int j = 0; j < 4; ++j)
                acc[i][j] = __builtin_amdgcn_mfma_f32_16x16x32_f16(afh[i], bcur[j], acc[i][j], 0, 0, 0);
        #pragma unroll
        for (int i = 0; i < 4; ++i)
            #pragma unroll
            for (int j = 0; j < 4; ++j)
                acc[i][j] = __builtin_amdgcn_mfma_f32_16x16x32_f16(afl[i], bcur[j], acc[i][j], 0, 0, 0);
        if (kt + 1 < nkt) {
            #pragma unroll
            for (int f = 0; f < 4; ++f) bcur[f] = bnxt[f];
        }
        cur ^= 1;
    }
    #pragma unroll
    for (int i = 0; i < 4; ++i) {
        int row0 = m0 + mw + i * 16 + lk8 * 4;   // C/D: col=lane&15, row=(lane>>4)*4+reg (m89)
        #pragma unroll
        for (int j = 0; j < 4; ++j) {
            int col = n0 + nw + j * 16 + l15;
            float bv = bias[col];
            int ct = 2;                            // 2 = identity
            if (actMode) {
                if (col < NKQV_) ct = (col % 320) >> 6;            // 0 k,1 q,2 v,3 b,4 g
                else { int m12 = (col - NKQV_) % 12; ct = (m12 < 8) ? 0 : 3; }  // p1/p2 relu, p3 sigm
            }
            #pragma unroll
            for (int rg = 0; rg < 4; ++rg) {
                float y = acc[i][j][rg] + bv;
                if (ct == 0 || ct == 1) y = fmaxf(y, 0.f);
                else if (ct >= 3) y = sigm(y);
                Yo[(size_t)(row0 + rg) * ldy + col] = y;
            }
        }
    }
}

// ---- gemm2 variant: 64x128 tile (4 waves, each 64M x 32N) for 2x the block count.
// Grid (N/128, M/64) = 512 blocks = 2 blocks/CU (vs 1 for 128^2) -> double TLP on the
// latency-critical K=512 GEMM. Same proven 2-phase schedule; A staged (2 GLD16/thread),
// B direct frag-linear. Y = (Ah+Al)*Bh + bias (identity epilogue).
__global__ __launch_bounds__(256, 6) void gemm_x2_g2(const u16* __restrict__ Ah, const u16* __restrict__ Al,
                                                     const u16* __restrict__ BTf,
                                                     const float* __restrict__ bias,
                                                     float* __restrict__ Yo, int ldy, int Kdim) {
    __shared__ __align__(16) u16 lds[2][2][2048];   // 2 buf x {AH,AL} x [64 rows][32 k] = 16 KB
    const int tid = threadIdx.x, lane = tid & 63, w = tid >> 6;
    const int nw = w * 32;                           // wave's 32-col slice
    const int l15 = lane & 15, lk8 = lane >> 4;
    const int lke = (lk8 ^ (l15 & 3) ^ ((l15 >> 2) & 3)) * 8;   // swizzled k-slot for A frag reads
    const int gx = gridDim.x;
    const int nb = gx * gridDim.y;
    const int orig = blockIdx.y * gx + blockIdx.x;
    const int per = nb >> 3;
    const int swz = (orig & 7) * per + (orig >> 3);
    const int m0 = (swz / gx) * 64, n0 = (swz % gx) * 128;
    const int nkt = Kdim >> 5;

    auto stageA = [&](int buf, int k0) {
        int row = tid >> 2, s = tid & 3;
        int kc = ((s ^ (row & 3) ^ ((row >> 2) & 3)) << 3);
        int wub = ((tid & ~63) << 3);
        size_t offA = (size_t)(m0 + row) * Kdim + k0 + kc;
        GLD16(Ah + offA, &lds[buf][0][wub]);
        GLD16(Al + offA, &lds[buf][1][wub]);
    };

    size_t bBase[2];
    #pragma unroll
    for (int f = 0; f < 2; ++f)
        bBase[f] = ((size_t)(((n0 + nw) >> 4) + f) * nkt << 9) + lane * 8;

    v4f acc[4][2] = {};
    stageA(0, 0);
    v8h bcur[2];
    #pragma unroll
    for (int f = 0; f < 2; ++f) bcur[f] = *(const v8h*)(BTf + bBase[f]);
    int cur = 0;
    for (int kt = 0; kt < nkt; ++kt) {
        __syncthreads();
        if (kt + 1 < nkt) stageA(cur ^ 1, (kt + 1) << 5);
        v8h bnxt[2];
        if (kt + 1 < nkt) {
            const size_t ko = (size_t)(kt + 1) << 9;
            #pragma unroll
            for (int f = 0; f < 2; ++f) bnxt[f] = *(const v8h*)(BTf + bBase[f] + ko);
        }
        v8h afh[4], afl[4];
        #pragma unroll
        for (int f = 0; f < 4; ++f) {
            int ra = (f * 16 + l15) * 32 + lke;
            afh[f] = *(const v8h*)&lds[cur][0][ra];
            afl[f] = *(const v8h*)&lds[cur][1][ra];
        }
        #pragma unroll
        for (int i = 0; i < 4; ++i)
            #pragma unroll
            for (int j = 0; j < 2; ++j)
                acc[i][j] = __builtin_amdgcn_mfma_f32_16x16x32_f16(afh[i], bcur[j], acc[i][j], 0, 0, 0);
        #pragma unroll
        for (int i = 0; i < 4; ++i)
            #pragma unroll
            for (int j = 0; j < 2; ++j)
                acc[i][j] = __builtin_amdgcn_mfma_f32_16x16x32_f16(afl[i], bcur[j], acc[i][j], 0, 0, 0);
        if (kt + 1 < nkt) {
            #pragma unroll
            for (int f = 0; f < 2; ++f) bcur[f] = bnxt[f];
        }
        cur ^= 1;
    }
    #pragma unroll
    for (int i = 0; i < 4; ++i) {
        int row0 = m0 + i * 16 + lk8 * 4;        // C/D: col=lane&15, row=(lane>>4)*4+reg (m89)
        #pragma unroll
        for (int j = 0; j < 2; ++j) {
            int col = n0 + nw + j * 16 + l15;
            float bv = bias[col];
            #pragma unroll
            for (int rg = 0; rg < 4; ++rg)
                Yo[(size_t)(row0 + rg) * ldy + col] = acc[i][j][rg] + bv;
        }
    }
}

// ---- scan phase 1: per (chunk,head) local scan from zero + decay products ----
// Y1 is PRE-ACTIVATED: k->relu, q->relu, v->id, b->sigm, g->sigm, p1/p2->relu, p3->sigm.
// CL record (49 vectors of 64 floats): [0,32)=kc[r*4+e], [32,40)=vc[r], [40,44)=sc[e], [44,48)=Pg[e], 48=Pb
__global__ __launch_bounds__(64) void scan_p1(const float* __restrict__ Y1, const float* __restrict__ OC,
                                              const int* __restrict__ term, float* __restrict__ CL) {
    const int b = blockIdx.x, c = b / H_, h = b % H_, lane = threadIdx.x;
    float kc[R_][ETA_] = {}, vc[R_] = {}, sc[ETA_] = {};
    float Pg[ETA_] = {1.f, 1.f, 1.f, 1.f}, Pb = 1.f;
    for (int t = c * LC_; t < c * LC_ + LC_; ++t) {
        const float* row = Y1 + (size_t)t * N1_;
        const float* bh = row + h * 320;
        float rk = bh[lane], vv = bh[128 + lane], sb = bh[192 + lane], sg = bh[256 + lane];
        const float* pp = row + NKQV_ + h * 12;
        float nt = 1.f - (float)term[t];
        float vals = vv * sb, dbv = (1.f - sb) * nt;
        float occ[R_];
        #pragma unroll
        for (int r = 0; r < R_; ++r) occ[r] = OC[t * R_ + r];
        #pragma unroll
        for (int e = 0; e < ETA_; ++e) {
            float gam = sg * pp[8 + e];
            float kg = rk * pp[e] * gam;
            float dgv = (1.f - gam) * nt;
            sc[e] = dgv * sc[e] + kg;
            Pg[e] *= dgv;
            #pragma unroll
            for (int r = 0; r < R_; ++r) kc[r][e] = dgv * kc[r][e] + kg * occ[r];
        }
        Pb *= dbv;
        #pragma unroll
        for (int r = 0; r < R_; ++r) vc[r] = dbv * vc[r] + vals * occ[r];
    }
    float* out = CL + (size_t)b * 49 * 64;
    #pragma unroll
    for (int r = 0; r < R_; ++r)
        #pragma unroll
        for (int e = 0; e < ETA_; ++e) out[(r * 4 + e) * 64 + lane] = kc[r][e];
    #pragma unroll
    for (int r = 0; r < R_; ++r) out[(32 + r) * 64 + lane] = vc[r];
    #pragma unroll
    for (int e = 0; e < ETA_; ++e) out[(40 + e) * 64 + lane] = sc[e];
    #pragma unroll
    for (int e = 0; e < ETA_; ++e) out[(44 + e) * 64 + lane] = Pg[e];
    out[48 * 64 + lane] = Pb;
}

// ---- scan phase 2 (element-parallel): 352 one-wave blocks; each thread owns one state scalar ----
__global__ __launch_bounds__(64) void scan_comb(const float* __restrict__ CL, float* __restrict__ CI,
                                                const float* __restrict__ TK, const float* __restrict__ TV,
                                                const float* __restrict__ SP) {
    const int gid = blockIdx.x * 64 + threadIdx.x;
    const int lane = gid & 63;
    const int hv = gid >> 6;          // 0..351
    const int h = hv / 44;
    const int v = hv % 44;
    float x;
    int dvec;
    if (v < 32) {
        int r = v >> 2, e = v & 3;
        x = TK[((size_t)r * H_ + h) * E_ + lane * 4 + e];
        dvec = 44 + e;
    } else if (v < 40) {
        int r = v - 32;
        x = TV[((size_t)r * H_ + h) * DH_ + lane];
        dvec = 48;
    } else {
        int e = v - 40;
        x = SP[(size_t)h * E_ + lane * 4 + e];
        dvec = 44 + e;
    }
    const float* clb = CL + (size_t)h * 49 * 64 + (size_t)v * 64 + lane;
    const float* dcb = CL + (size_t)h * 49 * 64 + (size_t)dvec * 64 + lane;
    float* cib = CI + (size_t)h * 44 * 64 + (size_t)v * 64 + lane;
    const size_t sCL = (size_t)H_ * 49 * 64;
    const size_t sCI = (size_t)H_ * 44 * 64;
    #pragma unroll 8
    for (int c = 0; c < NC_; ++c) {
        cib[(size_t)c * sCI] = x;
        float cl = clb[(size_t)c * sCL];
        float d  = dcb[(size_t)c * sCL];
        x = fmaf(d, x, cl);
    }
}

// ---- scan phase 3: re-scan with carry-in, emit attn (fp16 hi/lo, row-major S x 512) ----
__global__ __launch_bounds__(64) void scan_p3(const float* __restrict__ Y1, const float* __restrict__ OC,
                                              const int* __restrict__ term, const float* __restrict__ CI,
                                              u16* __restrict__ attnH, u16* __restrict__ attnL) {
    const int b = blockIdx.x, c = b / H_, h = b % H_, lane = threadIdx.x;
    float kc[R_][ETA_], vc[R_], sc[ETA_];
    const float* ci = CI + (size_t)b * 44 * 64;
    #pragma unroll
    for (int r = 0; r < R_; ++r)
        #pragma unroll
        for (int e = 0; e < ETA_; ++e) kc[r][e] = ci[(r * 4 + e) * 64 + lane];
    #pragma unroll
    for (int r = 0; r < R_; ++r) vc[r] = ci[(32 + r) * 64 + lane];
    #pragma unroll
    for (int e = 0; e < ETA_; ++e) sc[e] = ci[(40 + e) * 64 + lane];
    for (int t = c * LC_; t < c * LC_ + LC_; ++t) {
        const float* row = Y1 + (size_t)t * N1_;
        const float* bh = row + h * 320;
        float rk = bh[lane], rq = bh[64 + lane], vv = bh[128 + lane], sb = bh[192 + lane], sg = bh[256 + lane];
        const float* pp = row + NKQV_ + h * 12;
        float nt = 1.f - (float)term[t];
        float vals = vv * sb, dbv = (1.f - sb) * nt;
        float occ[R_];
        #pragma unroll
        for (int r = 0; r < R_; ++r) occ[r] = OC[t * R_ + r];
        float qe[ETA_];
        #pragma unroll
        for (int e = 0; e < ETA_; ++e) {
            float gam = sg * pp[8 + e];
            float kg = rk * pp[e] * gam;
            float dgv = (1.f - gam) * nt;
            qe[e] = rq * pp[4 + e];
            sc[e] = dgv * sc[e] + kg;
            #pragma unroll
            for (int r = 0; r < R_; ++r) kc[r][e] = dgv * kc[r][e] + kg * occ[r];
        }
        #pragma unroll
        for (int r = 0; r < R_; ++r) vc[r] = dbv * vc[r] + vals * occ[r];
        float kdq[R_], nrm = 0.f;
        #pragma unroll
        for (int r = 0; r < R_; ++r) {
            float s = 0.f;
            #pragma unroll
            for (int e = 0; e < ETA_; ++e) s += kc[r][e] * qe[e];
            kdq[r] = s;
        }
        #pragma unroll
        for (int e = 0; e < ETA_; ++e) nrm += sc[e] * qe[e];
        #pragma unroll
        for (int m = 1; m < 64; m <<= 1) {
            #pragma unroll
            for (int r = 0; r < R_; ++r) kdq[r] += __shfl_xor(kdq[r], m);
            nrm += __shfl_xor(nrm, m);
        }
        float kv = 0.f;
        #pragma unroll
        for (int r = 0; r < R_; ++r) kv += vc[r] * kdq[r];
        float at = kv / (2.f * R_ * nrm + 1e-5f);
        size_t oi = (size_t)t * (H_ * DH_) + h * DH_ + lane;
        u16 hi = f2h(at);
        attnH[oi] = hi;
        attnL[oi] = f2h(at - h2f(hi));
    }
}

extern "C" void kernel_launch(void* const* d_in, const int* in_sizes, int n_in,
                              void* d_out, int out_size, void* d_ws, size_t ws_size,
                              hipStream_t stream) {
    const float* inputs = (const float*)d_in[0];
    const int*   term   = (const int*)d_in[1];
    const float* Wk     = (const float*)d_in[2];
    const float* bk     = (const float*)d_in[3];
    const float* Wp     = (const float*)d_in[4];
    const float* bp     = (const float*)d_in[5];
    const float* Wproj  = (const float*)d_in[6];
    const float* bproj  = (const float*)d_in[7];
    const float* TK     = (const float*)d_in[8];
    const float* TV     = (const float*)d_in[9];
    const float* SP     = (const float*)d_in[10];
    const float* tick   = (const float*)d_in[11];
    float* out = (float*)d_out;

    char* w = (char*)d_ws;
    u16* AbfH   = (u16*)w;  w += (size_t)S_ * D_ * 2;          // 8 MB  (row-major)
    u16* AbfL   = (u16*)w;  w += (size_t)S_ * D_ * 2;          // 8 MB
    u16* BTh    = (u16*)w;  w += (size_t)N1_ * D_ * 2;         // 5.5 MB (frag-linear)
    u16* WpTh   = (u16*)w;  w += (size_t)D_ * 512 * 2;         // 1 MB   (frag-linear)
    u16* attnH  = (u16*)w;  w += (size_t)S_ * 512 * 2;         // 4 MB   (row-major)
    u16* attnL  = (u16*)w;  w += (size_t)S_ * 512 * 2;         // 4 MB
    float* biasb = (float*)w; w += (size_t)N1_ * 4;
    float* Y1   = (float*)w; w += (size_t)S_ * N1_ * 4;        // 44 MB
    float* OC   = (float*)w; w += (size_t)S_ * R_ * 4;
    float* CL   = (float*)w; w += (size_t)NC_ * H_ * 49 * 64 * 4;  // 25.7 MB
    float* CI   = (float*)w; w += (size_t)NC_ * H_ * 44 * 64 * 4;  // 23.1 MB

    prep_all<<<PB_TOTAL, 256, 0, stream>>>(inputs, Wk, Wp, Wproj, bk, bp, tick,
                                           AbfH, AbfL, BTh, WpTh, biasb, OC);
    gemm_x2_hyb<<<dim3(N1_ / 128, S_ / 128), 256, 0, stream>>>(AbfH, AbfL, BTh, biasb, Y1, N1_, D_, 1);
    scan_p1<<<NC_ * H_, 64, 0, stream>>>(Y1, OC, term, CL);
    scan_comb<<<(H_ * 44 * 64) / 64, 64, 0, stream>>>(CL, CI, TK, TV, SP);
    scan_p3<<<NC_ * H_, 64, 0, stream>>>(Y1, OC, term, CI, attnH, attnL);
    gemm_x2_g2<<<dim3(1024 / 128, S_ / 64), 256, 0, stream>>>(attnH, attnL, WpTh, bproj, out, D_, 512);
}

// Round 14
// 154.537 us; speedup vs baseline: 3.9568x; 1.0118x over previous
//
#include <hip/hip_runtime.h>
#include <hip/hip_bf16.h>

// ---- problem constants ----
#define S_    4096
#define D_    1024
#define H_    8
#define DH_   64
#define ETA_  4
#define R_    8
#define E_    256
#define NC_   256          // scan chunks
#define LC_   (S_/NC_)     // 16 steps per chunk
#define N1_   2688         // padded N for GEMM1 (21*128)
#define NKQV_ 2560
#define NP_   96
#define PIF   3.14159265358979323846

// prep_all block-range boundaries
#define PB_CVT    2048                 // inputs fp32->fp16 hi/lo split (row-major)
#define PB_TRWK   (PB_CVT + 640)       // W_kqv transpose -> frag-linear (16 k-tiles x 40 n-tiles)
#define PB_TRWP   (PB_TRWK + 32)       // W_p transpose (16 x 2)
#define PB_TRWPJ  (PB_TRWP + 128)      // W_proj transpose (8 x 16)
#define PB_OC     (PB_TRWPJ + 128)     // oscillator table
#define PB_BIAS   (PB_OC + 11)         // bias1
#define PB_TOTAL  PB_BIAS

typedef unsigned short u16;
typedef unsigned int   u32;
typedef _Float16 v8h __attribute__((ext_vector_type(8)));
typedef float v4f __attribute__((ext_vector_type(4)));

__device__ __forceinline__ u16 f2h(float f) {
    _Float16 h = (_Float16)f;                 // RTN
    return __builtin_bit_cast(unsigned short, h);
}
__device__ __forceinline__ float h2f(u16 u) {
    return (float)__builtin_bit_cast(_Float16, u);
}
__device__ __forceinline__ float sigm(float x) { return 1.f / (1.f + expf(-x)); }

// async global->LDS, 16 B per lane; LDS dest = wave-uniform base + lane*16
#define GLD16(gp, lp) __builtin_amdgcn_global_load_lds( \
    (const __attribute__((address_space(1))) u32*)(const void*)(gp), \
    (__attribute__((address_space(3))) u32*)(void*)(lp), 16, 0, 0)

// Fragment-linear layout (B operands): tile (nt = nrow/16, kt = k/32) of 512 fp16 = 1 KB at
// ((nt*nkt + kt) << 9); element at lane*8 + j, lane=(nrow&15)+((k&31)>>3)*16, j=k&7.

// ---- transpose 64x64 tile -> fp16 frag-linear ----
__device__ __forceinline__ void tr64h(float (*tile)[65], const float* __restrict__ src, int K, int Nsrc,
                                      u16* __restrict__ dH, int rowOff, int k0, int n0, int t) {
    const int cc = t & 63, rr = t >> 6;
    const int nkt = K >> 5;
    #pragma unroll
    for (int i = 0; i < 16; ++i) {
        int kk = rr * 16 + i;
        tile[kk][cc] = (n0 + cc < Nsrc) ? src[(size_t)(k0 + kk) * Nsrc + n0 + cc] : 0.f;
    }
    __syncthreads();
    #pragma unroll
    for (int i = 0; i < 16; ++i) {
        int nn = rr * 16 + i;
        int nrow = rowOff + n0 + nn, k = k0 + cc;
        int nt = nrow >> 4, kt = k >> 5;
        int ln = (nrow & 15) + (((k & 31) >> 3) << 4), j = k & 7;
        dH[((size_t)(nt * nkt + kt) << 9) + ln * 8 + j] = f2h(tile[cc][nn]);
    }
}

// ---- fused prep: cvt inputs (hi/lo row-major), 3 transposes (frag), oscillator, bias ----
__global__ __launch_bounds__(256) void prep_all(const float* __restrict__ inputs,
                                                const float* __restrict__ Wk, const float* __restrict__ Wp,
                                                const float* __restrict__ Wproj,
                                                const float* __restrict__ bk, const float* __restrict__ bp,
                                                const float* __restrict__ tick,
                                                u16* __restrict__ AbfH, u16* __restrict__ AbfL,
                                                u16* __restrict__ BTh, u16* __restrict__ WpTh,
                                                float* __restrict__ biasb, float* __restrict__ OC) {
    __shared__ float tile[64][65];
    const int b = blockIdx.x, t = threadIdx.x;
    if (b < PB_CVT) {
        int i = b * 256 + t;                       // 8 elems per thread, row-major
        const float4* xp = (const float4*)inputs;
        float4 a = xp[2 * i], bb = xp[2 * i + 1];
        float v[8] = {a.x, a.y, a.z, a.w, bb.x, bb.y, bb.z, bb.w};
        unsigned hh[8], ll[8];
        #pragma unroll
        for (int j = 0; j < 8; ++j) {
            u16 h = f2h(v[j]);
            hh[j] = h;
            ll[j] = f2h(v[j] - h2f(h));
        }
        uint4 rh, rl;
        rh.x = hh[0] | (hh[1] << 16); rh.y = hh[2] | (hh[3] << 16);
        rh.z = hh[4] | (hh[5] << 16); rh.w = hh[6] | (hh[7] << 16);
        rl.x = ll[0] | (ll[1] << 16); rl.y = ll[2] | (ll[3] << 16);
        rl.z = ll[4] | (ll[5] << 16); rl.w = ll[6] | (ll[7] << 16);
        ((uint4*)AbfH)[i] = rh;
        ((uint4*)AbfL)[i] = rl;
    } else if (b < PB_TRWK) {
        int i = b - PB_CVT;
        tr64h(tile, Wk, D_, NKQV_, BTh, 0, (i % 16) * 64, (i / 16) * 64, t);
    } else if (b < PB_TRWP) {
        int i = b - PB_TRWK;
        tr64h(tile, Wp, D_, NP_, BTh, NKQV_, (i % 16) * 64, (i / 16) * 64, t);
    } else if (b < PB_TRWPJ) {
        int i = b - PB_TRWP;
        tr64h(tile, Wproj, 512, D_, WpTh, 0, (i % 8) * 64, (i / 8) * 64, t);
    } else if (b < PB_OC) {
        int idx = (b - PB_TRWPJ) * 256 + t;
        int tt = idx / R_, r = idx % R_;
        float start = (float)(-PIF), stop = (float)PIF;
        float step = __fdiv_rn(__fsub_rn(stop, start), 7.0f);
        float om = __fadd_rn(start, __fmul_rn((float)r, step));
        float tk = __fadd_rn(tick[0], (float)(tt + 1));
        OC[idx] = cosf(__fmul_rn(tk, om));
    } else {
        int n = (b - PB_OC) * 256 + t;
        if (n < N1_)
            biasb[n] = n < NKQV_ ? bk[n] : (n < NKQV_ + NP_ ? bp[n - NKQV_] : 0.f);
    }
}

// ---- hybrid split-fp16 x2 GEMM (R9-proven, 60.8 us): A (hi/lo) via LDS double-buffered
// global_load_lds, B (hi) direct from global frag-linear, register-double-buffered.
// Y = (Ah+Al)*Bh + bias. 128x128 tile, 4 waves, BK=32. actMode=1: fused activations.
__global__ __launch_bounds__(256, 3) void gemm_x2_hyb(const u16* __restrict__ Ah, const u16* __restrict__ Al,
                                                      const u16* __restrict__ BTf,
                                                      const float* __restrict__ bias,
                                                      float* __restrict__ Yo, int ldy, int Kdim, int actMode) {
    __shared__ __align__(16) u16 lds[2][2][4096];   // 2 buf x {AH,AL} x [128 rows][32 k] = 32 KB
    const int tid = threadIdx.x, lane = tid & 63, w = tid >> 6;
    const int mw = (w >> 1) * 64, nw = (w & 1) * 64;
    const int l15 = lane & 15, lk8 = lane >> 4;
    const int lke = (lk8 ^ (l15 & 3) ^ ((l15 >> 2) & 3)) * 8;   // swizzled k-slot for A frag reads
    // XCD-aware block swizzle (total blocks % 8 == 0)
    const int gx = gridDim.x;
    const int nb = gx * gridDim.y;
    const int orig = blockIdx.y * gx + blockIdx.x;
    const int per = nb >> 3;
    const int swz = (orig & 7) * per + (orig >> 3);
    const int m0 = (swz / gx) * 128, n0 = (swz % gx) * 128;
    const int nkt = Kdim >> 5;

    auto stageA = [&](int buf, int k0) {
        #pragma unroll
        for (int c = 0; c < 2; ++c) {
            int u = tid + (c << 8);                               // 0..511 chunk index
            int row = u >> 2, s = u & 3;
            int kc = ((s ^ (row & 3) ^ ((row >> 2) & 3)) << 3);   // pre-swizzled global chunk
            int wub = ((u & ~63) << 3);                           // wave-uniform LDS elem offset
            size_t offA = (size_t)(m0 + row) * Kdim + k0 + kc;
            GLD16(Ah + offA, &lds[buf][0][wub]);
            GLD16(Al + offA, &lds[buf][1][wub]);
        }
    };

    // B frag-linear bases (per-wave column block nw)
    size_t bBase[4];
    #pragma unroll
    for (int f = 0; f < 4; ++f)
        bBase[f] = ((size_t)(((n0 + nw) >> 4) + f) * nkt << 9) + lane * 8;

    v4f acc[4][4] = {};
    stageA(0, 0);
    v8h bcur[4];
    #pragma unroll
    for (int f = 0; f < 4; ++f) bcur[f] = *(const v8h*)(BTf + bBase[f]);
    int cur = 0;
    for (int kt = 0; kt < nkt; ++kt) {
        __syncthreads();                      // buf[cur] A staged; prev frag reads done
        if (kt + 1 < nkt) stageA(cur ^ 1, (kt + 1) << 5);
        v8h bnxt[4];
        if (kt + 1 < nkt) {
            const size_t ko = (size_t)(kt + 1) << 9;
            #pragma unroll
            for (int f = 0; f < 4; ++f) bnxt[f] = *(const v8h*)(BTf + bBase[f] + ko);
        }
        v8h afh[4], afl[4];
        #pragma unroll
        for (int f = 0; f < 4; ++f) {
            int ra = (mw + f * 16 + l15) * 32 + lke;
            afh[f] = *(const v8h*)&lds[cur][0][ra];
            afl[f] = *(const v8h*)&lds[cur][1][ra];
        }
        #pragma unroll
        for (int i = 0; i < 4; ++i)
            #pragma unroll
            for (int j = 0; j < 4; ++j)
                acc[i][j] = __builtin_amdgcn_mfma_f32_16x16x32_f16(afh[i], bcur[j], acc[i][j], 0, 0, 0);
        #pragma unroll
        for (int i = 0; i < 4; ++i)
            #pragma unroll
            for (int j = 0; j < 4; ++j)
                acc[i][j] = __builtin_amdgcn_mfma_f32_16x16x32_f16(afl[i], bcur[j], acc[i][j], 0, 0, 0);
        if (kt + 1 < nkt) {
            #pragma unroll
            for (int f = 0; f < 4; ++f) bcur[f] = bnxt[f];
        }
        cur ^= 1;
    }
    #pragma unroll
    for (int i = 0; i < 4; ++i) {
        int row0 = m0 + mw + i * 16 + lk8 * 4;   // C/D: col=lane&15, row=(lane>>4)*4+reg (m89)
        #pragma unroll
        for (int j = 0; j < 4; ++j) {
            int col = n0 + nw + j * 16 + l15;
            float bv = bias[col];
            int ct = 2;                            // 2 = identity
            if (actMode) {
                if (col < NKQV_) ct = (col % 320) >> 6;            // 0 k,1 q,2 v,3 b,4 g
                else { int m12 = (col - NKQV_) % 12; ct = (m12 < 8) ? 0 : 3; }  // p1/p2 relu, p3 sigm
            }
            #pragma unroll
            for (int rg = 0; rg < 4; ++rg) {
                float y = acc[i][j][rg] + bv;
                if (ct == 0 || ct == 1) y = fmaxf(y, 0.f);
                else if (ct >= 3) y = sigm(y);
                Yo[(size_t)(row0 + rg) * ldy + col] = y;
            }
        }
    }
}

// ---- gemm2 variant: 64x128 tile (4 waves, each 64M x 32N), 512 blocks = 2 blocks/CU ----
__global__ __launch_bounds__(256, 6) void gemm_x2_g2(const u16* __restrict__ Ah, const u16* __restrict__ Al,
                                                     const u16* __restrict__ BTf,
                                                     const float* __restrict__ bias,
                                                     float* __restrict__ Yo, int ldy, int Kdim) {
    __shared__ __align__(16) u16 lds[2][2][2048];   // 2 buf x {AH,AL} x [64 rows][32 k] = 16 KB
    const int tid = threadIdx.x, lane = tid & 63, w = tid >> 6;
    const int nw = w * 32;                           // wave's 32-col slice
    const int l15 = lane & 15, lk8 = lane >> 4;
    const int lke = (lk8 ^ (l15 & 3) ^ ((l15 >> 2) & 3)) * 8;   // swizzled k-slot for A frag reads
    const int gx = gridDim.x;
    const int nb = gx * gridDim.y;
    const int orig = blockIdx.y * gx + blockIdx.x;
    const int per = nb >> 3;
    const int swz = (orig & 7) * per + (orig >> 3);
    const int m0 = (swz / gx) * 64, n0 = (swz % gx) * 128;
    const int nkt = Kdim >> 5;

    auto stageA = [&](int buf, int k0) {
        int row = tid >> 2, s = tid & 3;
        int kc = ((s ^ (row & 3) ^ ((row >> 2) & 3)) << 3);
        int wub = ((tid & ~63) << 3);
        size_t offA = (size_t)(m0 + row) * Kdim + k0 + kc;
        GLD16(Ah + offA, &lds[buf][0][wub]);
        GLD16(Al + offA, &lds[buf][1][wub]);
    };

    size_t bBase[2];
    #pragma unroll
    for (int f = 0; f < 2; ++f)
        bBase[f] = ((size_t)(((n0 + nw) >> 4) + f) * nkt << 9) + lane * 8;

    v4f acc[4][2] = {};
    stageA(0, 0);
    v8h bcur[2];
    #pragma unroll
    for (int f = 0; f < 2; ++f) bcur[f] = *(const v8h*)(BTf + bBase[f]);
    int cur = 0;
    for (int kt = 0; kt < nkt; ++kt) {
        __syncthreads();
        if (kt + 1 < nkt) stageA(cur ^ 1, (kt + 1) << 5);
        v8h bnxt[2];
        if (kt + 1 < nkt) {
            const size_t ko = (size_t)(kt + 1) << 9;
            #pragma unroll
            for (int f = 0; f < 2; ++f) bnxt[f] = *(const v8h*)(BTf + bBase[f] + ko);
        }
        v8h afh[4], afl[4];
        #pragma unroll
        for (int f = 0; f < 4; ++f) {
            int ra = (f * 16 + l15) * 32 + lke;
            afh[f] = *(const v8h*)&lds[cur][0][ra];
            afl[f] = *(const v8h*)&lds[cur][1][ra];
        }
        #pragma unroll
        for (int i = 0; i < 4; ++i)
            #pragma unroll
            for (int j = 0; j < 2; ++j)
                acc[i][j] = __builtin_amdgcn_mfma_f32_16x16x32_f16(afh[i], bcur[j], acc[i][j], 0, 0, 0);
        #pragma unroll
        for (int i = 0; i < 4; ++i)
            #pragma unroll
            for (int j = 0; j < 2; ++j)
                acc[i][j] = __builtin_amdgcn_mfma_f32_16x16x32_f16(afl[i], bcur[j], acc[i][j], 0, 0, 0);
        if (kt + 1 < nkt) {
            #pragma unroll
            for (int f = 0; f < 2; ++f) bcur[f] = bnxt[f];
        }
        cur ^= 1;
    }
    #pragma unroll
    for (int i = 0; i < 4; ++i) {
        int row0 = m0 + i * 16 + lk8 * 4;        // C/D: col=lane&15, row=(lane>>4)*4+reg (m89)
        #pragma unroll
        for (int j = 0; j < 2; ++j) {
            int col = n0 + nw + j * 16 + l15;
            float bv = bias[col];
            #pragma unroll
            for (int rg = 0; rg < 4; ++rg)
                Yo[(size_t)(row0 + rg) * ldy + col] = acc[i][j][rg] + bv;
        }
    }
}

// ---- scan phase 1 (2 waves per block, r-split): wave w owns r in [4w, 4w+4) ----
// Y1 is PRE-ACTIVATED. CL record (49 x 64 floats): [0,32)=kc[r*4+e], [32,40)=vc[r],
// [40,44)=sc[e], [44,48)=Pg[e], 48=Pb. sc/Pg/Pb written by wave 0.
__global__ __launch_bounds__(128) void scan_p1(const float* __restrict__ Y1, const float* __restrict__ OC,
                                               const int* __restrict__ term, float* __restrict__ CL) {
    const int b = blockIdx.x, c = b / H_, h = b % H_;
    const int tid = threadIdx.x, lane = tid & 63, wv = tid >> 6, r0 = wv * 4;
    float kc[4][ETA_] = {}, vc[4] = {}, sc[ETA_] = {};
    float Pg[ETA_] = {1.f, 1.f, 1.f, 1.f}, Pb = 1.f;
    for (int t = c * LC_; t < c * LC_ + LC_; ++t) {
        const float* row = Y1 + (size_t)t * N1_;
        const float* bh = row + h * 320;
        float rk = bh[lane], vv = bh[128 + lane], sb = bh[192 + lane], sg = bh[256 + lane];
        const float* pp = row + NKQV_ + h * 12;
        float nt = 1.f - (float)term[t];
        float vals = vv * sb, dbv = (1.f - sb) * nt;
        float occ[4];
        #pragma unroll
        for (int r = 0; r < 4; ++r) occ[r] = OC[t * R_ + r0 + r];
        #pragma unroll
        for (int e = 0; e < ETA_; ++e) {
            float gam = sg * pp[8 + e];
            float kg = rk * pp[e] * gam;
            float dgv = (1.f - gam) * nt;
            if (wv == 0) { sc[e] = dgv * sc[e] + kg; Pg[e] *= dgv; }
            #pragma unroll
            for (int r = 0; r < 4; ++r) kc[r][e] = dgv * kc[r][e] + kg * occ[r];
        }
        if (wv == 0) Pb *= dbv;
        #pragma unroll
        for (int r = 0; r < 4; ++r) vc[r] = dbv * vc[r] + vals * occ[r];
    }
    float* out = CL + (size_t)b * 49 * 64;
    #pragma unroll
    for (int r = 0; r < 4; ++r)
        #pragma unroll
        for (int e = 0; e < ETA_; ++e) out[((r0 + r) * 4 + e) * 64 + lane] = kc[r][e];
    #pragma unroll
    for (int r = 0; r < 4; ++r) out[(32 + r0 + r) * 64 + lane] = vc[r];
    if (wv == 0) {
        #pragma unroll
        for (int e = 0; e < ETA_; ++e) out[(40 + e) * 64 + lane] = sc[e];
        #pragma unroll
        for (int e = 0; e < ETA_; ++e) out[(44 + e) * 64 + lane] = Pg[e];
        out[48 * 64 + lane] = Pb;
    }
}

// ---- scan phase 2 (element-parallel): 352 one-wave blocks; each thread owns one state scalar ----
__global__ __launch_bounds__(64) void scan_comb(const float* __restrict__ CL, float* __restrict__ CI,
                                                const float* __restrict__ TK, const float* __restrict__ TV,
                                                const float* __restrict__ SP) {
    const int gid = blockIdx.x * 64 + threadIdx.x;
    const int lane = gid & 63;
    const int hv = gid >> 6;          // 0..351
    const int h = hv / 44;
    const int v = hv % 44;
    float x;
    int dvec;
    if (v < 32) {
        int r = v >> 2, e = v & 3;
        x = TK[((size_t)r * H_ + h) * E_ + lane * 4 + e];
        dvec = 44 + e;
    } else if (v < 40) {
        int r = v - 32;
        x = TV[((size_t)r * H_ + h) * DH_ + lane];
        dvec = 48;
    } else {
        int e = v - 40;
        x = SP[(size_t)h * E_ + lane * 4 + e];
        dvec = 44 + e;
    }
    const float* clb = CL + (size_t)h * 49 * 64 + (size_t)v * 64 + lane;
    const float* dcb = CL + (size_t)h * 49 * 64 + (size_t)dvec * 64 + lane;
    float* cib = CI + (size_t)h * 44 * 64 + (size_t)v * 64 + lane;
    const size_t sCL = (size_t)H_ * 49 * 64;
    const size_t sCI = (size_t)H_ * 44 * 64;
    #pragma unroll 8
    for (int c = 0; c < NC_; ++c) {
        cib[(size_t)c * sCI] = x;
        float cl = clb[(size_t)c * sCL];
        float d  = dcb[(size_t)c * sCL];
        x = fmaf(d, x, cl);
    }
}

// ---- scan phase 3 (2 waves per block, r-split): wave w owns r in [4w, 4w+4) ----
// Per t: each wave updates its 4 kc/vc states, butterflies 4 kdq (+nrm on wave0),
// computes partial kv; wave1 passes partial via double-buffered LDS; wave0 emits attn.
__global__ __launch_bounds__(128) void scan_p3(const float* __restrict__ Y1, const float* __restrict__ OC,
                                               const int* __restrict__ term, const float* __restrict__ CI,
                                               u16* __restrict__ attnH, u16* __restrict__ attnL) {
    __shared__ float kvbuf[2][64];
    const int b = blockIdx.x, c = b / H_, h = b % H_;
    const int tid = threadIdx.x, lane = tid & 63, wv = tid >> 6, r0 = wv * 4;
    float kc[4][ETA_], vc[4], sc[ETA_] = {};
    const float* ci = CI + (size_t)b * 44 * 64;
    #pragma unroll
    for (int r = 0; r < 4; ++r)
        #pragma unroll
        for (int e = 0; e < ETA_; ++e) kc[r][e] = ci[((r0 + r) * 4 + e) * 64 + lane];
    #pragma unroll
    for (int r = 0; r < 4; ++r) vc[r] = ci[(32 + r0 + r) * 64 + lane];
    if (wv == 0) {
        #pragma unroll
        for (int e = 0; e < ETA_; ++e) sc[e] = ci[(40 + e) * 64 + lane];
    }
    int tt = 0;
    for (int t = c * LC_; t < c * LC_ + LC_; ++t, ++tt) {
        const float* row = Y1 + (size_t)t * N1_;
        const float* bh = row + h * 320;
        float rk = bh[lane], rq = bh[64 + lane], vv = bh[128 + lane], sb = bh[192 + lane], sg = bh[256 + lane];
        const float* pp = row + NKQV_ + h * 12;
        float nt = 1.f - (float)term[t];
        float vals = vv * sb, dbv = (1.f - sb) * nt;
        float occ[4];
        #pragma unroll
        for (int r = 0; r < 4; ++r) occ[r] = OC[t * R_ + r0 + r];
        float qe[ETA_];
        #pragma unroll
        for (int e = 0; e < ETA_; ++e) {
            float gam = sg * pp[8 + e];
            float kg = rk * pp[e] * gam;
            float dgv = (1.f - gam) * nt;
            qe[e] = rq * pp[4 + e];
            if (wv == 0) sc[e] = dgv * sc[e] + kg;
            #pragma unroll
            for (int r = 0; r < 4; ++r) kc[r][e] = dgv * kc[r][e] + kg * occ[r];
        }
        #pragma unroll
        for (int r = 0; r < 4; ++r) vc[r] = dbv * vc[r] + vals * occ[r];
        float kdq[4], nrm = 0.f;
        #pragma unroll
        for (int r = 0; r < 4; ++r) {
            float s = 0.f;
            #pragma unroll
            for (int e = 0; e < ETA_; ++e) s += kc[r][e] * qe[e];
            kdq[r] = s;
        }
        if (wv == 0) {
            #pragma unroll
            for (int e = 0; e < ETA_; ++e) nrm += sc[e] * qe[e];
        }
        #pragma unroll
        for (int m = 1; m < 64; m <<= 1) {
            #pragma unroll
            for (int r = 0; r < 4; ++r) kdq[r] += __shfl_xor(kdq[r], m);
            if (wv == 0) nrm += __shfl_xor(nrm, m);
        }
        float pkv = 0.f;
        #pragma unroll
        for (int r = 0; r < 4; ++r) pkv += vc[r] * kdq[r];
        if (wv == 1) kvbuf[tt & 1][lane] = pkv;
        __syncthreads();
        if (wv == 0) {
            float kv = pkv + kvbuf[tt & 1][lane];
            float at = kv / (2.f * R_ * nrm + 1e-5f);
            size_t oi = (size_t)t * (H_ * DH_) + h * DH_ + lane;
            u16 hi = f2h(at);
            attnH[oi] = hi;
            attnL[oi] = f2h(at - h2f(hi));
        }
    }
}

extern "C" void kernel_launch(void* const* d_in, const int* in_sizes, int n_in,
                              void* d_out, int out_size, void* d_ws, size_t ws_size,
                              hipStream_t stream) {
    const float* inputs = (const float*)d_in[0];
    const int*   term   = (const int*)d_in[1];
    const float* Wk     = (const float*)d_in[2];
    const float* bk     = (const float*)d_in[3];
    const float* Wp     = (const float*)d_in[4];
    const float* bp     = (const float*)d_in[5];
    const float* Wproj  = (const float*)d_in[6];
    const float* bproj  = (const float*)d_in[7];
    const float* TK     = (const float*)d_in[8];
    const float* TV     = (const float*)d_in[9];
    const float* SP     = (const float*)d_in[10];
    const float* tick   = (const float*)d_in[11];
    float* out = (float*)d_out;

    char* w = (char*)d_ws;
    u16* AbfH   = (u16*)w;  w += (size_t)S_ * D_ * 2;          // 8 MB  (row-major)
    u16* AbfL   = (u16*)w;  w += (size_t)S_ * D_ * 2;          // 8 MB
    u16* BTh    = (u16*)w;  w += (size_t)N1_ * D_ * 2;         // 5.5 MB (frag-linear)
    u16* WpTh   = (u16*)w;  w += (size_t)D_ * 512 * 2;         // 1 MB   (frag-linear)
    u16* attnH  = (u16*)w;  w += (size_t)S_ * 512 * 2;         // 4 MB   (row-major)
    u16* attnL  = (u16*)w;  w += (size_t)S_ * 512 * 2;         // 4 MB
    float* biasb = (float*)w; w += (size_t)N1_ * 4;
    float* Y1   = (float*)w; w += (size_t)S_ * N1_ * 4;        // 44 MB
    float* OC   = (float*)w; w += (size_t)S_ * R_ * 4;
    float* CL   = (float*)w; w += (size_t)NC_ * H_ * 49 * 64 * 4;  // 25.7 MB
    float* CI   = (float*)w; w += (size_t)NC_ * H_ * 44 * 64 * 4;  // 23.1 MB

    prep_all<<<PB_TOTAL, 256, 0, stream>>>(inputs, Wk, Wp, Wproj, bk, bp, tick,
                                           AbfH, AbfL, BTh, WpTh, biasb, OC);
    gemm_x2_hyb<<<dim3(N1_ / 128, S_ / 128), 256, 0, stream>>>(AbfH, AbfL, BTh, biasb, Y1, N1_, D_, 1);
    scan_p1<<<NC_ * H_, 128, 0, stream>>>(Y1, OC, term, CL);
    scan_comb<<<(H_ * 44 * 64) / 64, 64, 0, stream>>>(CL, CI, TK, TV, SP);
    scan_p3<<<NC_ * H_, 128, 0, stream>>>(Y1, OC, term, CI, attnH, attnL);
    gemm_x2_g2<<<dim3(1024 / 128, S_ / 64), 256, 0, stream>>>(attnH, attnL, WpTh, bproj, out, D_, 512);
}